// Round 2
// baseline (198.290 us; speedup 1.0000x reference)
//
#include <hip/hip_runtime.h>

// out[b,a,x,y] = C0 * (s x Fn)[a], Fn = periodic 4-neighbor sum of s.
// L[s][r][a] = -eps_{sra}; 6 nonzero coefficients loaded from Lp, -C0 folded in.
//
// Register-rolling stencil: each wave owns 4 consecutive x-rows (full Y row:
// 64 lanes x 8 floats) and walks x keeping 4 row-sets (3 comps) in registers.
// Reads per output row drop from 3x to 1.5x at the L1 level -> frees the
// per-CU outstanding-miss budget that capped us at ~3.3 TB/s.
// Block = 4 waves = 16-row slab; XCD-chunked swizzle so adjacent slabs share
// an XCD L2 (halo re-fetches hit L2, HBM FETCH stays ~1x).

constexpr int B = 32, X = 512, Y = 512;
constexpr int XY = X * Y;

struct RowC { float4 lo, hi; };   // one spin component, 8 consecutive y per lane
struct Row3 { RowC c[3]; };       // all 3 spin components of one x-row

__device__ __forceinline__ void load_row(const float* __restrict__ sb, size_t rowoff, Row3& r)
{
    #pragma unroll
    for (int c = 0; c < 3; ++c) {
        const float* p = sb + (size_t)c * XY + rowoff;
        r.c[c].lo = *(const float4*)(p);
        r.c[c].hi = *(const float4*)(p + 4);
    }
}

__device__ __forceinline__ void compute_store(const Row3& U, const Row3& Cn, const Row3& Dn,
                                              float* __restrict__ ob, size_t rowoff, int lane,
                                              float cA0, float cB0, float cA1,
                                              float cB1, float cA2, float cB2)
{
    float Fn[3][8];
    float sc[3][8];
    #pragma unroll
    for (int c = 0; c < 3; ++c) {
        const float4 c0 = Cn.c[c].lo, c1 = Cn.c[c].hi;
        const float4 u0 = U.c[c].lo,  u1 = U.c[c].hi;
        const float4 d0 = Dn.c[c].lo, d1 = Dn.c[c].hi;
        // periodic y-neighbors via adjacent lanes (verified round 1, absmax=0)
        const float lf = __shfl(c1.w, (lane + 63) & 63, 64);
        const float rt = __shfl(c0.x, (lane + 1) & 63, 64);

        sc[c][0] = c0.x; sc[c][1] = c0.y; sc[c][2] = c0.z; sc[c][3] = c0.w;
        sc[c][4] = c1.x; sc[c][5] = c1.y; sc[c][6] = c1.z; sc[c][7] = c1.w;

        Fn[c][0] = u0.x + d0.x + lf   + c0.y;
        Fn[c][1] = u0.y + d0.y + c0.x + c0.z;
        Fn[c][2] = u0.z + d0.z + c0.y + c0.w;
        Fn[c][3] = u0.w + d0.w + c0.z + c1.x;
        Fn[c][4] = u1.x + d1.x + c0.w + c1.y;
        Fn[c][5] = u1.y + d1.y + c1.x + c1.z;
        Fn[c][6] = u1.z + d1.z + c1.y + c1.w;
        Fn[c][7] = u1.w + d1.w + c1.z + rt;
    }

    float o[3][8];
    #pragma unroll
    for (int e = 0; e < 8; ++e) {
        o[0][e] = cA0 * (sc[1][e] * Fn[2][e]) + cB0 * (sc[2][e] * Fn[1][e]);
        o[1][e] = cA1 * (sc[0][e] * Fn[2][e]) + cB1 * (sc[2][e] * Fn[0][e]);
        o[2][e] = cA2 * (sc[0][e] * Fn[1][e]) + cB2 * (sc[1][e] * Fn[0][e]);
    }

    #pragma unroll
    for (int a = 0; a < 3; ++a) {
        float* q = ob + (size_t)a * XY + rowoff;
        *(float4*)(q)     = make_float4(o[a][0], o[a][1], o[a][2], o[a][3]);
        *(float4*)(q + 4) = make_float4(o[a][4], o[a][5], o[a][6], o[a][7]);
    }
}

__global__ __launch_bounds__(256)
void psi0_kernel(const float* __restrict__ s,
                 const float* __restrict__ C0p,
                 const float* __restrict__ Lp,
                 float* __restrict__ out)
{
    const int tid  = threadIdx.x;
    const int lane = tid & 63;
    const int wv   = tid >> 6;

    // XCD-chunked swizzle (bijective: 1024 = 8 * 128): adjacent slabs -> same XCD L2.
    const int bid = blockIdx.x;
    const int g   = (bid & 7) * 128 + (bid >> 3);

    const int b    = g >> 5;              // 32 slabs of 16 rows per batch
    const int slab = g & 31;
    const int x0   = slab * 16 + wv * 4;  // this wave's 4-row strip
    const int y0   = lane << 3;

    const float C0 = C0p[0];
    const float cA0 = -C0 * Lp[15];  // a=0: (s=1,r=2)
    const float cB0 = -C0 * Lp[21];  // a=0: (s=2,r=1)
    const float cA1 = -C0 * Lp[7];   // a=1: (s=0,r=2)
    const float cB1 = -C0 * Lp[19];  // a=1: (s=2,r=0)
    const float cA2 = -C0 * Lp[5];   // a=2: (s=0,r=1)
    const float cB2 = -C0 * Lp[11];  // a=2: (s=1,r=0)

    const float* sb = s   + (size_t)b * 3 * XY + y0;
    float*       ob = out + (size_t)b * 3 * XY + y0;

    auto roff = [](int x) { return (size_t)((x + X) & (X - 1)) * Y; };

    Row3 Ar, Br, Cr, Dr;
    // startup: 4 row-sets (24 dwordx4 loads) in flight at once
    load_row(sb, roff(x0 - 1), Ar);
    load_row(sb, roff(x0),     Br);
    load_row(sb, roff(x0 + 1), Cr);
    load_row(sb, roff(x0 + 2), Dr);

    // step 0: out row x0 from (A,B,C); then A slot is free -> prefetch x0+3
    compute_store(Ar, Br, Cr, ob, (size_t)x0 * Y, lane, cA0, cB0, cA1, cB1, cA2, cB2);
    load_row(sb, roff(x0 + 3), Ar);

    // step 1: out row x0+1 from (B,C,D); B free -> prefetch x0+4
    compute_store(Br, Cr, Dr, ob, (size_t)(x0 + 1) * Y, lane, cA0, cB0, cA1, cB1, cA2, cB2);
    load_row(sb, roff(x0 + 4), Br);

    // step 2: out row x0+2 from (C,D,A)
    compute_store(Cr, Dr, Ar, ob, (size_t)(x0 + 2) * Y, lane, cA0, cB0, cA1, cB1, cA2, cB2);

    // step 3: out row x0+3 from (D,A,B)
    compute_store(Dr, Ar, Br, ob, (size_t)(x0 + 3) * Y, lane, cA0, cB0, cA1, cB1, cA2, cB2);
}

extern "C" void kernel_launch(void* const* d_in, const int* in_sizes, int n_in,
                              void* d_out, int out_size, void* d_ws, size_t ws_size,
                              hipStream_t stream)
{
    const float* s   = (const float*)d_in[0];
    // d_in[1] = t (unused: coeff is t-independent with a single cc entry)
    const float* C0p = (const float*)d_in[2];
    const float* Lp  = (const float*)d_in[3];
    float* out = (float*)d_out;

    const int blocks = B * (X / 16);   // 1024 blocks x 256 threads; 16-row slab per block
    psi0_kernel<<<blocks, 256, 0, stream>>>(s, C0p, Lp, out);
}

// Round 6
// 182.247 us; speedup vs baseline: 1.0880x; 1.0880x over previous
//
#include <hip/hip_runtime.h>

// out[b,a,x,y] = C0 * (s x Fn)[a], Fn = periodic 4-neighbor sum of s.
// L[s][r][a] = -eps_{sra}; 6 nonzero coefficients loaded from Lp, -C0 folded in.
// Epilogue uses the EXPLICIT per-a pairing verified in rounds 1-2 (absmax=0.0):
//   o[0] = cA0*(sc1*Fn2) + cB0*(sc2*Fn1)
//   o[1] = cA1*(sc0*Fn2) + cB1*(sc2*Fn0)
//   o[2] = cA2*(sc0*Fn1) + cB2*(sc1*Fn0)
// (Round-4's cyclic (a+1)%3/(a+2)%3 form silently swapped cA1/cB1 -> sign flip
//  of the a=1 plane. Do not "simplify" this again.)
//
// Strategy: maximize per-wave memory-level parallelism AND occupancy at once.
//  - Each thread produces a float4 on TWO adjacent x-rows (x, x+1), loading the
//    4 stencil rows (x-1..x+2) x 3 components as 12 independent dwordx4 that
//    are ALL hoisted before any compute.
//  - 4096 blocks x 256 threads; __launch_bounds__(256,4) caps VGPR at 128 so
//    >=16 waves/CU stay resident.
//  - 2 rows/thread cuts L1-level read amplification 3.0x -> 2.0x.
//  - Non-temporal stores: output is never re-read; keep L2 for halo capture.

constexpr int B = 32, X = 512, Y = 512;
constexpr int XY = X * Y;

typedef float f32x4 __attribute__((ext_vector_type(4)));

__device__ __forceinline__ void nt_store4(float* p, float a, float b, float c, float d)
{
    f32x4 v = { a, b, c, d };
    __builtin_nontemporal_store(v, (f32x4*)p);
}

__global__ __launch_bounds__(256, 4)
void psi0_kernel(const float* __restrict__ s,
                 const float* __restrict__ C0p,
                 const float* __restrict__ Lp,
                 float* __restrict__ out)
{
    const int tid = threadIdx.x;
    const int ty  = tid & 127;           // 128 threads span one row (512/4)
    const int rp  = tid >> 7;            // which row-pair in this block
    const int bid = blockIdx.x;
    const int b   = bid >> 7;            // 128 row-quads per batch
    const int x   = ((bid & 127) << 2) + (rp << 1);  // first output row (even)
    const int y0  = ty << 2;

    const int xm  = (x == 0) ? X - 1 : x - 1;
    const int xp1 = x + 1;                            // <= 511, never wraps
    const int xp2 = (x + 2 == X) ? 0 : x + 2;
    const int ym  = (y0 == 0)     ? Y - 1 : y0 - 1;
    const int yp  = (y0 + 4 == Y) ? 0     : y0 + 4;

    const float C0  = C0p[0];
    const float cA0 = -C0 * Lp[15];  // a=0: (s=1,r=2)
    const float cB0 = -C0 * Lp[21];  // a=0: (s=2,r=1)
    const float cA1 = -C0 * Lp[7];   // a=1: (s=0,r=2)
    const float cB1 = -C0 * Lp[19];  // a=1: (s=2,r=0)
    const float cA2 = -C0 * Lp[5];   // a=2: (s=0,r=1)
    const float cB2 = -C0 * Lp[11];  // a=2: (s=1,r=0)

    const size_t base = (size_t)b * 3 * XY;
    const size_t rB = (size_t)x   * Y + y0;   // center row of output 0
    const size_t rA = (size_t)xm  * Y + y0;
    const size_t rC = (size_t)xp1 * Y + y0;   // center row of output 1
    const size_t rD = (size_t)xp2 * Y + y0;

    // ---- hoisted load phase: 12 independent dwordx4 (the HBM misses) ----
    float4 Av[3], Bv[3], Cv[3], Dv[3];
    #pragma unroll
    for (int c = 0; c < 3; ++c) {
        const float* p = s + base + (size_t)c * XY;
        Av[c] = *(const float4*)(p + rA);
        Bv[c] = *(const float4*)(p + rB);
        Cv[c] = *(const float4*)(p + rC);
        Dv[c] = *(const float4*)(p + rD);
    }
    // y-edge scalars (L1/L2 hits on neighbors' lines)
    float lfB[3], rtB[3], lfC[3], rtC[3];
    #pragma unroll
    for (int c = 0; c < 3; ++c) {
        const float* p = s + base + (size_t)c * XY;
        lfB[c] = p[(size_t)x   * Y + ym];
        rtB[c] = p[(size_t)x   * Y + yp];
        lfC[c] = p[(size_t)xp1 * Y + ym];
        rtC[c] = p[(size_t)xp1 * Y + yp];
    }

    // ---- compute + store row x (center Bv, up Av, dn Cv) ----
    {
        float Fn[3][4], sc[3][4];
        #pragma unroll
        for (int c = 0; c < 3; ++c) {
            const float4 cc = Bv[c], uu = Av[c], dd = Cv[c];
            sc[c][0] = cc.x; sc[c][1] = cc.y; sc[c][2] = cc.z; sc[c][3] = cc.w;
            Fn[c][0] = uu.x + dd.x + lfB[c] + cc.y;
            Fn[c][1] = uu.y + dd.y + cc.x   + cc.z;
            Fn[c][2] = uu.z + dd.z + cc.y   + cc.w;
            Fn[c][3] = uu.w + dd.w + cc.z   + rtB[c];
        }
        float o0[4], o1[4], o2[4];
        #pragma unroll
        for (int e = 0; e < 4; ++e) {
            o0[e] = cA0 * (sc[1][e] * Fn[2][e]) + cB0 * (sc[2][e] * Fn[1][e]);
            o1[e] = cA1 * (sc[0][e] * Fn[2][e]) + cB1 * (sc[2][e] * Fn[0][e]);
            o2[e] = cA2 * (sc[0][e] * Fn[1][e]) + cB2 * (sc[1][e] * Fn[0][e]);
        }
        nt_store4(out + base + 0 * (size_t)XY + rB, o0[0], o0[1], o0[2], o0[3]);
        nt_store4(out + base + 1 * (size_t)XY + rB, o1[0], o1[1], o1[2], o1[3]);
        nt_store4(out + base + 2 * (size_t)XY + rB, o2[0], o2[1], o2[2], o2[3]);
    }

    // ---- compute + store row x+1 (center Cv, up Bv, dn Dv) ----
    {
        float Fn[3][4], sc[3][4];
        #pragma unroll
        for (int c = 0; c < 3; ++c) {
            const float4 cc = Cv[c], uu = Bv[c], dd = Dv[c];
            sc[c][0] = cc.x; sc[c][1] = cc.y; sc[c][2] = cc.z; sc[c][3] = cc.w;
            Fn[c][0] = uu.x + dd.x + lfC[c] + cc.y;
            Fn[c][1] = uu.y + dd.y + cc.x   + cc.z;
            Fn[c][2] = uu.z + dd.z + cc.y   + cc.w;
            Fn[c][3] = uu.w + dd.w + cc.z   + rtC[c];
        }
        float o0[4], o1[4], o2[4];
        #pragma unroll
        for (int e = 0; e < 4; ++e) {
            o0[e] = cA0 * (sc[1][e] * Fn[2][e]) + cB0 * (sc[2][e] * Fn[1][e]);
            o1[e] = cA1 * (sc[0][e] * Fn[2][e]) + cB1 * (sc[2][e] * Fn[0][e]);
            o2[e] = cA2 * (sc[0][e] * Fn[1][e]) + cB2 * (sc[1][e] * Fn[0][e]);
        }
        nt_store4(out + base + 0 * (size_t)XY + rC, o0[0], o0[1], o0[2], o0[3]);
        nt_store4(out + base + 1 * (size_t)XY + rC, o1[0], o1[1], o1[2], o1[3]);
        nt_store4(out + base + 2 * (size_t)XY + rC, o2[0], o2[1], o2[2], o2[3]);
    }
}

extern "C" void kernel_launch(void* const* d_in, const int* in_sizes, int n_in,
                              void* d_out, int out_size, void* d_ws, size_t ws_size,
                              hipStream_t stream)
{
    const float* s   = (const float*)d_in[0];
    // d_in[1] = t (unused: coeff is t-independent with a single cc entry)
    const float* C0p = (const float*)d_in[2];
    const float* Lp  = (const float*)d_in[3];
    float* out = (float*)d_out;

    const int blocks = B * (X / 4);   // 4096 blocks x 256 threads; 4 rows/block
    psi0_kernel<<<blocks, 256, 0, stream>>>(s, C0p, Lp, out);
}